// Round 1
// baseline (449.534 us; speedup 1.0000x reference)
//
#include <hip/hip_runtime.h>
#include <cstdint>

#define BQ 4
#define QPB 65536
#define QTOT (BQ*QPB)          /* 262144 */
#define TRIN 393216            /* 3*32*64*64 */
#define TRI_OUT (BQ*TRIN)      /* 1572864 */

typedef __attribute__((ext_vector_type(8))) __bf16 bf16x8;
typedef __attribute__((ext_vector_type(4))) float f32x4;

__device__ __forceinline__ unsigned short f2bf(float f) {
    unsigned u = __float_as_uint(f);
    u += 0x7fffu + ((u >> 16) & 1u);
    return (unsigned short)(u >> 16);
}
__device__ __forceinline__ float bf2f(unsigned short h) {
    return __uint_as_float(((unsigned)h) << 16);
}
__device__ __forceinline__ float silu_f(float x) {
    return x / (1.0f + __expf(-x));
}

// ---------------- K0: transpose+pad MLP weights to bf16 [N][K] ----------------
__global__ __launch_bounds__(256) void k_prep_w(
    const float* __restrict__ mw0, const float* __restrict__ mw1, const float* __restrict__ mw2,
    unsigned short* __restrict__ wt0, unsigned short* __restrict__ wt1, unsigned short* __restrict__ wt2)
{
    int idx = blockIdx.x * 256 + threadIdx.x;
    if (idx < 32768) {                       // wt0: [256][128], source mw0 [99][256]
        int n = idx >> 7, k = idx & 127;
        float v = (k < 99) ? mw0[k * 256 + n] : 0.0f;
        wt0[idx] = f2bf(v);
    } else if (idx < 98304) {                // wt1: [256][256], source mw1 [256][256]
        int r = idx - 32768;
        int n = r >> 8, k = r & 255;
        wt1[r] = f2bf(mw1[k * 256 + n]);
    } else if (idx < 163840) {               // wt2
        int r = idx - 98304;
        int n = r >> 8, k = r & 255;
        wt2[r] = f2bf(mw2[k * 256 + n]);
    }
}

// ---------------- K1: h = silu(z @ w1 + b1), [4][512] f32 ----------------
__global__ __launch_bounds__(256) void k_h(
    const float* __restrict__ z, const float* __restrict__ w1,
    const float* __restrict__ b1, float* __restrict__ hout)
{
    int gid = blockIdx.x * 256 + threadIdx.x;   // 2048 total
    int b = gid >> 9, n = gid & 511;
    float acc = b1[n];
    #pragma unroll 8
    for (int k = 0; k < 256; ++k)
        acc += z[b * 256 + k] * w1[k * 512 + n];
    hout[gid] = silu_f(acc);
}

// ---------------- K2: triplanes = h @ w2 + b2 (805 MB stream) ----------------
// writes f32 d_out ([b][p][c][y][x]) and channel-last ws copy ([b][p][y][x][c])
__global__ __launch_bounds__(256) void k_triplane(
    const float* __restrict__ w2, const float* __restrict__ b2,
    const float* __restrict__ h, float* __restrict__ outTri, float* __restrict__ triT)
{
    __shared__ float hs[2048];
    int t = threadIdx.x;
    #pragma unroll
    for (int i = 0; i < 8; ++i) hs[t + 256 * i] = h[t + 256 * i];
    __syncthreads();
    int j = (blockIdx.x * 256 + t) * 2;
    float ax[4] = {0.f, 0.f, 0.f, 0.f}, ay[4] = {0.f, 0.f, 0.f, 0.f};
    #pragma unroll 8
    for (int k = 0; k < 512; ++k) {
        float2 wv = *(const float2*)(w2 + (size_t)k * TRIN + j);
        #pragma unroll
        for (int b = 0; b < 4; ++b) {
            float hb = hs[b * 512 + k];
            ax[b] += hb * wv.x;
            ay[b] += hb * wv.y;
        }
    }
    float2 bj = *(const float2*)(b2 + j);
    int x = j & 63, y = (j >> 6) & 63, c = (j >> 12) & 31, p = j >> 17;
    #pragma unroll
    for (int b = 0; b < 4; ++b) {
        float vx = ax[b] + bj.x, vy = ay[b] + bj.y;
        float2 o; o.x = vx; o.y = vy;
        *(float2*)(outTri + (size_t)b * TRIN + j) = o;
        int tt = ((((b * 3 + p) * 64 + y) * 64 + x) << 5) + c;
        triT[tt] = vx;
        triT[tt + 32] = vy;     // x+1 (j even => same c,y,p)
    }
}

// ---------------- K4: fused sample + 3-layer MLP + heads ----------------
__global__ __launch_bounds__(256) void k_mlp(
    const float* __restrict__ qp, const float* __restrict__ triT,
    const unsigned short* __restrict__ wt0, const unsigned short* __restrict__ wt1,
    const unsigned short* __restrict__ wt2,
    const float* __restrict__ mb0, const float* __restrict__ mb1, const float* __restrict__ mb2,
    const float* __restrict__ sdf_w, const float* __restrict__ sdf_b,
    const float* __restrict__ occ_w, const float* __restrict__ occ_b,
    float* __restrict__ out)
{
    __shared__ __align__(16) unsigned char lds[65536];
    unsigned char* bufA = lds;
    unsigned char* bufB = lds + 32768;
    const int t = threadIdx.x;
    const int row0 = blockIdx.x * 64;

    // ---- gather phase: build X0 [64 rows][128 bf16], XOR-swizzled ----
    if (t < 192) {
        int lp = t & 63, plane = t >> 6;
        int gr = row0 + lp;
        int b = gr >> 16;
        float px = qp[3 * gr], py = qp[3 * gr + 1], pz = qp[3 * gr + 2];
        float u = (plane == 2) ? py : px;
        float v = (plane == 0) ? py : pz;
        u = fminf(fmaxf(u, -1.f), 1.f);
        v = fminf(fmaxf(v, -1.f), 1.f);
        float xf = (u + 1.f) * 31.5f;
        float yf = (v + 1.f) * 31.5f;
        float x0 = floorf(xf), y0 = floorf(yf);
        float wx = xf - x0, wy = yf - y0;
        int xi = min(max((int)x0, 0), 63);
        int yi = min(max((int)y0, 0), 63);
        int xi1 = min(xi + 1, 63), yi1 = min(yi + 1, 63);
        float w00 = (1.f - wx) * (1.f - wy), w01 = wx * (1.f - wy);
        float w10 = (1.f - wx) * wy,         w11 = wx * wy;
        int pb = (b * 3 + plane) * 64;
        const float4* p00 = (const float4*)(triT + (((pb + yi ) * 64 + xi ) << 5));
        const float4* p01 = (const float4*)(triT + (((pb + yi ) * 64 + xi1) << 5));
        const float4* p10 = (const float4*)(triT + (((pb + yi1) * 64 + xi ) << 5));
        const float4* p11 = (const float4*)(triT + (((pb + yi1) * 64 + xi1) << 5));
        int swzb = (lp & 7) << 4;
        #pragma unroll
        for (int pair = 0; pair < 4; ++pair) {
            unsigned tmp[4];
            #pragma unroll
            for (int hh = 0; hh < 2; ++hh) {
                float4 a = p00[pair * 2 + hh], bb = p01[pair * 2 + hh];
                float4 cc = p10[pair * 2 + hh], dd = p11[pair * 2 + hh];
                float o0 = w00 * a.x + w01 * bb.x + w10 * cc.x + w11 * dd.x;
                float o1 = w00 * a.y + w01 * bb.y + w10 * cc.y + w11 * dd.y;
                float o2 = w00 * a.z + w01 * bb.z + w10 * cc.z + w11 * dd.z;
                float o3 = w00 * a.w + w01 * bb.w + w10 * cc.w + w11 * dd.w;
                tmp[hh * 2]     = (unsigned)f2bf(o0) | ((unsigned)f2bf(o1) << 16);
                tmp[hh * 2 + 1] = (unsigned)f2bf(o2) | ((unsigned)f2bf(o3) << 16);
            }
            uint4 pk; pk.x = tmp[0]; pk.y = tmp[1]; pk.z = tmp[2]; pk.w = tmp[3];
            *(uint4*)(bufA + lp * 256 + ((plane * 64 + pair * 16) ^ swzb)) = pk;
        }
    } else {
        int lp = t - 192;
        int gr = row0 + lp;
        float px = qp[3 * gr], py = qp[3 * gr + 1], pz = qp[3 * gr + 2];
        int swzb = (lp & 7) << 4;
        uint4 pk;
        pk.x = (unsigned)f2bf(px) | ((unsigned)f2bf(py) << 16);
        pk.y = (unsigned)f2bf(pz);
        pk.z = 0u; pk.w = 0u;
        *(uint4*)(bufA + lp * 256 + (192 ^ swzb)) = pk;
        uint4 z4; z4.x = z4.y = z4.z = z4.w = 0u;
        *(uint4*)(bufA + lp * 256 + (208 ^ swzb)) = z4;
        *(uint4*)(bufA + lp * 256 + (224 ^ swzb)) = z4;
        *(uint4*)(bufA + lp * 256 + (240 ^ swzb)) = z4;
    }
    __syncthreads();

    const int lane = t & 63;
    const int wv = t >> 6;
    const int l15 = lane & 15;
    const int kg = lane >> 4;
    const int n0 = wv * 64;

    unsigned char* bin = bufA; int ldin = 256;
    unsigned char* bout = bufB;

    const unsigned short* wts[3] = {wt0, wt1, wt2};
    const float* mbs[3] = {mb0, mb1, mb2};
    const int Ksz[3] = {128, 256, 256};

    #pragma unroll 1
    for (int L = 0; L < 3; ++L) {
        const int K = Ksz[L];
        const unsigned short* wt = wts[L];
        f32x4 acc[4][4];
        #pragma unroll
        for (int rf = 0; rf < 4; ++rf)
            #pragma unroll
            for (int cf = 0; cf < 4; ++cf) {
                f32x4 zv = {0.f, 0.f, 0.f, 0.f};
                acc[rf][cf] = zv;
            }
        for (int k0 = 0; k0 < K; k0 += 32) {
            uint4 av[4], bv[4];
            #pragma unroll
            for (int rf = 0; rf < 4; ++rf) {
                int row = 16 * rf + l15;
                av[rf] = *(const uint4*)(bin + row * ldin + ((((k0 + kg * 8) * 2)) ^ ((row & 7) << 4)));
            }
            #pragma unroll
            for (int cf = 0; cf < 4; ++cf) {
                int n = n0 + 16 * cf + l15;
                bv[cf] = *(const uint4*)(wt + n * K + k0 + kg * 8);
            }
            #pragma unroll
            for (int rf = 0; rf < 4; ++rf)
                #pragma unroll
                for (int cf = 0; cf < 4; ++cf)
                    acc[rf][cf] = __builtin_amdgcn_mfma_f32_16x16x32_bf16(
                        __builtin_bit_cast(bf16x8, av[rf]),
                        __builtin_bit_cast(bf16x8, bv[cf]),
                        acc[rf][cf], 0, 0, 0);
        }
        const float* mb = mbs[L];
        #pragma unroll
        for (int cf = 0; cf < 4; ++cf) {
            int col = n0 + 16 * cf + l15;
            float bias = mb[col];
            #pragma unroll
            for (int rf = 0; rf < 4; ++rf) {
                #pragma unroll
                for (int jj = 0; jj < 4; ++jj) {
                    int row = 16 * rf + kg * 4 + jj;
                    float vvv = silu_f(acc[rf][cf][jj] + bias);
                    *(unsigned short*)(bout + row * 512 + ((col * 2) ^ ((row & 7) << 4))) = f2bf(vvv);
                }
            }
        }
        __syncthreads();
        unsigned char* tswap = bin; bin = bout; bout = tswap;
        ldin = 512;
    }

    // ---- heads: sdf / occ from final activations (bin, ld=512) ----
    {
        int row = 16 * wv + l15;
        int gr = row0 + row;
        float aS = 0.f, aO = 0.f;
        int kb = kg * 64;
        #pragma unroll
        for (int i = 0; i < 8; ++i) {
            int k = kb + i * 8;
            uint4 xv = *(const uint4*)(bin + row * 512 + ((k * 2) ^ ((row & 7) << 4)));
            const unsigned* xu = (const unsigned*)&xv;
            float4 s0 = *(const float4*)(sdf_w + k);
            float4 s1 = *(const float4*)(sdf_w + k + 4);
            float4 o0 = *(const float4*)(occ_w + k);
            float4 o1 = *(const float4*)(occ_w + k + 4);
            float xr[8];
            #pragma unroll
            for (int q = 0; q < 4; ++q) {
                xr[2 * q]     = bf2f((unsigned short)(xu[q] & 0xffffu));
                xr[2 * q + 1] = bf2f((unsigned short)(xu[q] >> 16));
            }
            aS += xr[0] * s0.x + xr[1] * s0.y + xr[2] * s0.z + xr[3] * s0.w
                + xr[4] * s1.x + xr[5] * s1.y + xr[6] * s1.z + xr[7] * s1.w;
            aO += xr[0] * o0.x + xr[1] * o0.y + xr[2] * o0.z + xr[3] * o0.w
                + xr[4] * o1.x + xr[5] * o1.y + xr[6] * o1.z + xr[7] * o1.w;
        }
        aS += __shfl_xor(aS, 16);
        aS += __shfl_xor(aS, 32);
        aO += __shfl_xor(aO, 16);
        aO += __shfl_xor(aO, 32);
        if (kg == 0) {
            out[TRI_OUT + gr] = aS + sdf_b[0];
            out[TRI_OUT + QTOT + gr] = aO + occ_b[0];
        }
    }
}

extern "C" void kernel_launch(void* const* d_in, const int* in_sizes, int n_in,
                              void* d_out, int out_size, void* d_ws, size_t ws_size,
                              hipStream_t stream)
{
    const float* z     = (const float*)d_in[0];
    const float* qp    = (const float*)d_in[1];
    const float* w1    = (const float*)d_in[2];
    const float* b1    = (const float*)d_in[3];
    const float* w2    = (const float*)d_in[4];
    const float* b2    = (const float*)d_in[5];
    const float* mw0   = (const float*)d_in[6];
    const float* mb0   = (const float*)d_in[7];
    const float* mw1   = (const float*)d_in[8];
    const float* mb1   = (const float*)d_in[9];
    const float* mw2   = (const float*)d_in[10];
    const float* mb2   = (const float*)d_in[11];
    const float* sdf_w = (const float*)d_in[12];
    const float* sdf_b = (const float*)d_in[13];
    const float* occ_w = (const float*)d_in[14];
    const float* occ_b = (const float*)d_in[15];
    float* out = (float*)d_out;
    char* ws = (char*)d_ws;

    float* h_ws          = (float*)(ws);              // 8192 B
    unsigned short* wt0  = (unsigned short*)(ws + 8192);    // 65536 B
    unsigned short* wt1  = (unsigned short*)(ws + 73728);   // 131072 B
    unsigned short* wt2  = (unsigned short*)(ws + 204800);  // 131072 B
    float* triT          = (float*)(ws + 335872);     // 6291456 B

    k_prep_w<<<640, 256, 0, stream>>>(mw0, mw1, mw2, wt0, wt1, wt2);
    k_h<<<8, 256, 0, stream>>>(z, w1, b1, h_ws);
    k_triplane<<<768, 256, 0, stream>>>(w2, b2, h_ws, out, triT);
    k_mlp<<<4096, 256, 0, stream>>>(qp, triT, wt0, wt1, wt2,
                                    mb0, mb1, mb2, sdf_w, sdf_b, occ_w, occ_b, out);
}

// Round 2
// 406.341 us; speedup vs baseline: 1.1063x; 1.1063x over previous
//
#include <hip/hip_runtime.h>
#include <cstdint>

#define BQ 4
#define QPB 65536
#define QTOT (BQ*QPB)          /* 262144 */
#define TRIN 393216            /* 3*32*64*64 */
#define TRI_OUT (BQ*TRIN)      /* 1572864 */

typedef __attribute__((ext_vector_type(8))) __bf16 bf16x8;
typedef __attribute__((ext_vector_type(4))) float f32x4;

__device__ __forceinline__ unsigned short f2bf(float f) {
    unsigned u = __float_as_uint(f);
    u += 0x7fffu + ((u >> 16) & 1u);
    return (unsigned short)(u >> 16);
}
__device__ __forceinline__ float bf2f(unsigned short h) {
    return __uint_as_float(((unsigned)h) << 16);
}
__device__ __forceinline__ float silu_f(float x) {
    return x / (1.0f + __expf(-x));
}

// ---------------- K0: transpose+pad MLP weights to bf16 [N][K] ----------------
__global__ __launch_bounds__(256) void k_prep_w(
    const float* __restrict__ mw0, const float* __restrict__ mw1, const float* __restrict__ mw2,
    unsigned short* __restrict__ wt0, unsigned short* __restrict__ wt1, unsigned short* __restrict__ wt2)
{
    int idx = blockIdx.x * 256 + threadIdx.x;
    if (idx < 32768) {                       // wt0: [256][128], source mw0 [99][256]
        int n = idx >> 7, k = idx & 127;
        float v = (k < 99) ? mw0[k * 256 + n] : 0.0f;
        wt0[idx] = f2bf(v);
    } else if (idx < 98304) {                // wt1: [256][256], source mw1 [256][256]
        int r = idx - 32768;
        int n = r >> 8, k = r & 255;
        wt1[r] = f2bf(mw1[k * 256 + n]);
    } else if (idx < 163840) {               // wt2
        int r = idx - 98304;
        int n = r >> 8, k = r & 255;
        wt2[r] = f2bf(mw2[k * 256 + n]);
    }
}

// ---------------- K1: h = silu(z @ w1 + b1), [4][512] f32 ----------------
__global__ __launch_bounds__(256) void k_h(
    const float* __restrict__ z, const float* __restrict__ w1,
    const float* __restrict__ b1, float* __restrict__ hout)
{
    int gid = blockIdx.x * 256 + threadIdx.x;   // 2048 total
    int b = gid >> 9, n = gid & 511;
    float acc = b1[n];
    #pragma unroll 8
    for (int k = 0; k < 256; ++k)
        acc += z[b * 256 + k] * w1[k * 512 + n];
    hout[gid] = silu_f(acc);
}

// ---------------- K2: triplanes = h @ w2 + b2 (805 MB stream) ----------------
// thread owns (x,x+1) x (c,c+1): all writes are float2.
__global__ __launch_bounds__(128) void k_triplane(
    const float* __restrict__ w2, const float* __restrict__ b2,
    const float* __restrict__ h, float* __restrict__ outTri, float* __restrict__ triT)
{
    __shared__ float hs[2048];
    int t = threadIdx.x;
    #pragma unroll
    for (int i = 0; i < 16; ++i) hs[t + 128 * i] = h[t + 128 * i];
    __syncthreads();
    int g = blockIdx.x * 128 + t;            // 98304 threads
    int xh = g & 31, y = (g >> 5) & 63, chn = (g >> 11) & 15, p = g >> 15;
    int x = xh * 2, c = chn * 2;
    int j00 = ((p * 32 + c) * 64 + y) * 64 + x;
    int j10 = j00 + 4096;                    // c+1
    float a00[4] = {0,0,0,0}, a01[4] = {0,0,0,0}, a10[4] = {0,0,0,0}, a11[4] = {0,0,0,0};
    #pragma unroll 8
    for (int k = 0; k < 512; ++k) {
        float2 wv0 = *(const float2*)(w2 + (size_t)k * TRIN + j00);
        float2 wv1 = *(const float2*)(w2 + (size_t)k * TRIN + j10);
        #pragma unroll
        for (int b = 0; b < 4; ++b) {
            float hb = hs[b * 512 + k];
            a00[b] += hb * wv0.x; a01[b] += hb * wv0.y;
            a10[b] += hb * wv1.x; a11[b] += hb * wv1.y;
        }
    }
    float2 bj0 = *(const float2*)(b2 + j00);
    float2 bj1 = *(const float2*)(b2 + j10);
    int ttb = ((p * 64 + y) * 64 + x) * 32 + c;
    #pragma unroll
    for (int b = 0; b < 4; ++b) {
        float v00 = a00[b] + bj0.x, v01 = a01[b] + bj0.y;
        float v10 = a10[b] + bj1.x, v11 = a11[b] + bj1.y;
        float2 o0; o0.x = v00; o0.y = v01;
        float2 o1; o1.x = v10; o1.y = v11;
        *(float2*)(outTri + (size_t)b * TRIN + j00) = o0;
        *(float2*)(outTri + (size_t)b * TRIN + j10) = o1;
        int tt = b * TRIN + ttb;
        float2 t0; t0.x = v00; t0.y = v10;   // (x,   c..c+1)
        float2 t1; t1.x = v01; t1.y = v11;   // (x+1, c..c+1)
        *(float2*)(triT + tt) = t0;
        *(float2*)(triT + tt + 32) = t1;
    }
}

// ---------------- K4: fused sample + 3-layer MLP + heads ----------------
template<int K, int LDIN>
__device__ __forceinline__ void mlp_layer(
    const unsigned char* bin, unsigned char* bout,
    const unsigned short* __restrict__ wt, const float* __restrict__ mb,
    int lane, int wv)
{
    const int l15 = lane & 15;
    const int kg = lane >> 4;
    const int n0 = wv * 64;
    f32x4 acc[4][4];
    #pragma unroll
    for (int rf = 0; rf < 4; ++rf)
        #pragma unroll
        for (int cf = 0; cf < 4; ++cf) {
            f32x4 zv = {0.f, 0.f, 0.f, 0.f};
            acc[rf][cf] = zv;
        }
    #pragma unroll
    for (int k0 = 0; k0 < K; k0 += 32) {
        uint4 av[4], bv[4];
        #pragma unroll
        for (int rf = 0; rf < 4; ++rf) {
            int row = 16 * rf + l15;
            av[rf] = *(const uint4*)(bin + row * LDIN + ((2 * (k0 + kg * 8)) ^ ((row & 7) << 4)));
        }
        #pragma unroll
        for (int cf = 0; cf < 4; ++cf) {
            int n = n0 + 16 * cf + l15;
            bv[cf] = *(const uint4*)(wt + n * K + k0 + kg * 8);
        }
        __builtin_amdgcn_s_setprio(1);
        #pragma unroll
        for (int rf = 0; rf < 4; ++rf)
            #pragma unroll
            for (int cf = 0; cf < 4; ++cf)
                acc[rf][cf] = __builtin_amdgcn_mfma_f32_16x16x32_bf16(
                    __builtin_bit_cast(bf16x8, av[rf]),
                    __builtin_bit_cast(bf16x8, bv[cf]),
                    acc[rf][cf], 0, 0, 0);
        __builtin_amdgcn_s_setprio(0);
    }
    #pragma unroll
    for (int cf = 0; cf < 4; ++cf) {
        int col = n0 + 16 * cf + l15;
        float bias = mb[col];
        #pragma unroll
        for (int rf = 0; rf < 4; ++rf) {
            #pragma unroll
            for (int jj = 0; jj < 4; ++jj) {
                int row = 16 * rf + kg * 4 + jj;
                float vvv = silu_f(acc[rf][cf][jj] + bias);
                *(unsigned short*)(bout + row * 512 + ((col * 2) ^ ((row & 7) << 4))) = f2bf(vvv);
            }
        }
    }
    __syncthreads();
}

__global__ __launch_bounds__(256) void k_mlp(
    const float* __restrict__ qp, const float* __restrict__ triT,
    const unsigned short* __restrict__ wt0, const unsigned short* __restrict__ wt1,
    const unsigned short* __restrict__ wt2,
    const float* __restrict__ mb0, const float* __restrict__ mb1, const float* __restrict__ mb2,
    const float* __restrict__ sdf_w, const float* __restrict__ sdf_b,
    const float* __restrict__ occ_w, const float* __restrict__ occ_b,
    float* __restrict__ out)
{
    __shared__ __align__(16) unsigned char lds[65536];
    unsigned char* bufA = lds;
    unsigned char* bufB = lds + 32768;
    unsigned char* scr  = bufB;              // 192*32B coord scratch, dead after phase B
    const int t = threadIdx.x;

    // batch <-> XCD affinity (bijective: 4096 = 8 XCD * 512)
    const int bid = blockIdx.x;
    const int xcd = bid & 7;
    const int batch = xcd >> 1;
    const int brow = (bid >> 3) + ((xcd & 1) << 9);   // 0..1023
    const int row0 = batch * QPB + brow * 64;

    // ---- phase A: per (q,plane) corner offsets + weights -> scr ----
    if (t < 192) {
        int plane = t >> 6, q = t & 63;
        int gr = row0 + q;
        float px = qp[3 * gr], py = qp[3 * gr + 1], pz = qp[3 * gr + 2];
        float u = (plane == 2) ? py : px;
        float v = (plane == 0) ? py : pz;
        u = fminf(fmaxf(u, -1.f), 1.f);
        v = fminf(fmaxf(v, -1.f), 1.f);
        float xf = (u + 1.f) * 31.5f;
        float yf = (v + 1.f) * 31.5f;
        float x0 = floorf(xf), y0 = floorf(yf);
        float wx = xf - x0, wy = yf - y0;
        int xi = min(max((int)x0, 0), 63);
        int yi = min(max((int)y0, 0), 63);
        int xi1 = min(xi + 1, 63), yi1 = min(yi + 1, 63);
        int pb = (batch * 3 + plane) * 64;
        int4 offs;
        offs.x = ((pb + yi ) * 64 + xi ) << 5;
        offs.y = ((pb + yi ) * 64 + xi1) << 5;
        offs.z = ((pb + yi1) * 64 + xi ) << 5;
        offs.w = ((pb + yi1) * 64 + xi1) << 5;
        float4 w;
        w.x = (1.f - wx) * (1.f - wy); w.y = wx * (1.f - wy);
        w.z = (1.f - wx) * wy;         w.w = wx * wy;
        *(int4*)(scr + t * 32) = offs;
        *(float4*)(scr + t * 32 + 16) = w;
        if (plane == 0) {
            // pts + zero pad, X0 cols 96..127 (bytes 192..255)
            int swz = (q & 7) << 4;
            uint4 c0;
            c0.x = (unsigned)f2bf(px) | ((unsigned)f2bf(py) << 16);
            c0.y = (unsigned)f2bf(pz);
            c0.z = 0u; c0.w = 0u;
            uint4 z4; z4.x = z4.y = z4.z = z4.w = 0u;
            *(uint4*)(bufA + q * 256 + ((192) ^ swz)) = c0;
            *(uint4*)(bufA + q * 256 + ((208) ^ swz)) = z4;
            *(uint4*)(bufA + q * 256 + ((224) ^ swz)) = z4;
            *(uint4*)(bufA + q * 256 + ((240) ^ swz)) = z4;
        }
    }
    __syncthreads();

    // ---- phase B: coalesced gather+blend, 8 lanes per (q,plane) ----
    #pragma unroll
    for (int i = 0; i < 6; ++i) {
        int unit = i * 256 + t;              // 1536 = 192 * 8 quarters
        int quarter = unit & 7;
        int uc = unit >> 3;                  // = plane*64 + q
        const unsigned char* ce = scr + uc * 32;
        int4 offs = *(const int4*)ce;
        float4 w = *(const float4*)(ce + 16);
        const float* q0 = triT + offs.x + quarter * 4;
        const float* q1 = triT + offs.y + quarter * 4;
        const float* q2 = triT + offs.z + quarter * 4;
        const float* q3 = triT + offs.w + quarter * 4;
        float4 c0 = *(const float4*)q0;
        float4 c1 = *(const float4*)q1;
        float4 c2 = *(const float4*)q2;
        float4 c3 = *(const float4*)q3;
        float r0 = w.x * c0.x + w.y * c1.x + w.z * c2.x + w.w * c3.x;
        float r1 = w.x * c0.y + w.y * c1.y + w.z * c2.y + w.w * c3.y;
        float r2 = w.x * c0.z + w.y * c1.z + w.z * c2.z + w.w * c3.z;
        float r3 = w.x * c0.w + w.y * c1.w + w.z * c2.w + w.w * c3.w;
        int q = uc & 63, plane = uc >> 6;
        int colb = plane * 64 + quarter * 8;
        uint2 pk;
        pk.x = (unsigned)f2bf(r0) | ((unsigned)f2bf(r1) << 16);
        pk.y = (unsigned)f2bf(r2) | ((unsigned)f2bf(r3) << 16);
        *(uint2*)(bufA + q * 256 + (colb ^ ((q & 7) << 4))) = pk;
    }
    __syncthreads();

    const int lane = t & 63;
    const int wv = t >> 6;

    mlp_layer<128, 256>(bufA, bufB, wt0, mb0, lane, wv);
    mlp_layer<256, 512>(bufB, bufA, wt1, mb1, lane, wv);
    mlp_layer<256, 512>(bufA, bufB, wt2, mb2, lane, wv);

    // ---- heads: sdf / occ from final activations (bufB, ld=512) ----
    {
        const int l15 = lane & 15;
        const int kg = lane >> 4;
        int row = 16 * wv + l15;
        int gr = row0 + row;
        float aS = 0.f, aO = 0.f;
        int kb = kg * 64;
        #pragma unroll
        for (int i = 0; i < 8; ++i) {
            int k = kb + i * 8;
            uint4 xv = *(const uint4*)(bufB + row * 512 + ((k * 2) ^ ((row & 7) << 4)));
            const unsigned* xu = (const unsigned*)&xv;
            float4 s0 = *(const float4*)(sdf_w + k);
            float4 s1 = *(const float4*)(sdf_w + k + 4);
            float4 o0 = *(const float4*)(occ_w + k);
            float4 o1 = *(const float4*)(occ_w + k + 4);
            float xr[8];
            #pragma unroll
            for (int q = 0; q < 4; ++q) {
                xr[2 * q]     = bf2f((unsigned short)(xu[q] & 0xffffu));
                xr[2 * q + 1] = bf2f((unsigned short)(xu[q] >> 16));
            }
            aS += xr[0] * s0.x + xr[1] * s0.y + xr[2] * s0.z + xr[3] * s0.w
                + xr[4] * s1.x + xr[5] * s1.y + xr[6] * s1.z + xr[7] * s1.w;
            aO += xr[0] * o0.x + xr[1] * o0.y + xr[2] * o0.z + xr[3] * o0.w
                + xr[4] * o1.x + xr[5] * o1.y + xr[6] * o1.z + xr[7] * o1.w;
        }
        aS += __shfl_xor(aS, 16);
        aS += __shfl_xor(aS, 32);
        aO += __shfl_xor(aO, 16);
        aO += __shfl_xor(aO, 32);
        if (kg == 0) {
            out[TRI_OUT + gr] = aS + sdf_b[0];
            out[TRI_OUT + QTOT + gr] = aO + occ_b[0];
        }
    }
}

extern "C" void kernel_launch(void* const* d_in, const int* in_sizes, int n_in,
                              void* d_out, int out_size, void* d_ws, size_t ws_size,
                              hipStream_t stream)
{
    const float* z     = (const float*)d_in[0];
    const float* qp    = (const float*)d_in[1];
    const float* w1    = (const float*)d_in[2];
    const float* b1    = (const float*)d_in[3];
    const float* w2    = (const float*)d_in[4];
    const float* b2    = (const float*)d_in[5];
    const float* mw0   = (const float*)d_in[6];
    const float* mb0   = (const float*)d_in[7];
    const float* mw1   = (const float*)d_in[8];
    const float* mb1   = (const float*)d_in[9];
    const float* mw2   = (const float*)d_in[10];
    const float* mb2   = (const float*)d_in[11];
    const float* sdf_w = (const float*)d_in[12];
    const float* sdf_b = (const float*)d_in[13];
    const float* occ_w = (const float*)d_in[14];
    const float* occ_b = (const float*)d_in[15];
    float* out = (float*)d_out;
    char* ws = (char*)d_ws;

    float* h_ws          = (float*)(ws);                    // 8192 B
    unsigned short* wt0  = (unsigned short*)(ws + 8192);    // 65536 B
    unsigned short* wt1  = (unsigned short*)(ws + 73728);   // 131072 B
    unsigned short* wt2  = (unsigned short*)(ws + 204800);  // 131072 B
    float* triT          = (float*)(ws + 335872);           // 6291456 B

    k_prep_w<<<640, 256, 0, stream>>>(mw0, mw1, mw2, wt0, wt1, wt2);
    k_h<<<8, 256, 0, stream>>>(z, w1, b1, h_ws);
    k_triplane<<<768, 128, 0, stream>>>(w2, b2, h_ws, out, triT);
    k_mlp<<<4096, 256, 0, stream>>>(qp, triT, wt0, wt1, wt2,
                                    mb0, mb1, mb2, sdf_w, sdf_b, occ_w, occ_b, out);
}